// Round 6
// baseline (534.771 us; speedup 1.0000x reference)
//
#include <hip/hip_runtime.h>
#include <hip/hip_bf16.h>
#include <cstdint>
#include <cstddef>

#define B_     2
#define E_     196608
#define XD_    128
#define NREC_  12288
#define M_     (B_ * NREC_)

typedef __attribute__((ext_vector_type(8))) short short8;
typedef __attribute__((ext_vector_type(4))) float f32x4;

__device__ __forceinline__ unsigned short f2bf(float f) {
    union { float f; unsigned u; } v; v.f = f;
    unsigned r = v.u + 0x7FFFu + ((v.u >> 16) & 1u);
    return (unsigned short)(r >> 16);
}

// ---- FFN weight precompute only (512 blocks) ----
// L1T[n][k]: k<128 : (W2@L1_top)[k][n]; k>=128 : L1[k][n].  L2T[n][k] = L2[k][n].
// v[n] = sum_c b2[c]*L1[c][n]  (scaled by cnt in ffn).
__global__ __launch_bounds__(256) void pre_w(
        const float* __restrict__ W2, const float* __restrict__ b2,
        const float* __restrict__ L1, const float* __restrict__ L2,
        unsigned short* __restrict__ L1T, unsigned short* __restrict__ L2T,
        float* __restrict__ v) {
    int bid = blockIdx.x;
    int n = threadIdx.x;    // 0..255
    if (bid < 128) {
        int j = bid;
        float a0 = 0.f, a1 = 0.f, a2 = 0.f, a3 = 0.f;
        for (int c = 0; c < 128; c += 4) {
            a0 = fmaf(W2[j * 128 + c + 0], L1[(c + 0) * 256 + n], a0);
            a1 = fmaf(W2[j * 128 + c + 1], L1[(c + 1) * 256 + n], a1);
            a2 = fmaf(W2[j * 128 + c + 2], L1[(c + 2) * 256 + n], a2);
            a3 = fmaf(W2[j * 128 + c + 3], L1[(c + 3) * 256 + n], a3);
        }
        L1T[n * 256 + j] = f2bf((a0 + a1) + (a2 + a3));
        if (j == 0) {
            float s0 = 0.f, s1 = 0.f;
            for (int c = 0; c < 128; c += 2) {
                s0 = fmaf(b2[c + 0], L1[(c + 0) * 256 + n], s0);
                s1 = fmaf(b2[c + 1], L1[(c + 1) * 256 + n], s1);
            }
            v[n] = s0 + s1;
        }
    } else if (bid < 256) {
        int k = bid;                          // 128..255
        L1T[n * 256 + k] = f2bf(L1[k * 256 + n]);
    } else {
        int k = bid - 256;                    // 0..255
        L2T[n * 256 + k] = f2bf(L2[k * 256 + n]);
    }
}

// ---- scatter: edge-major, fully sequential x reads, atomic fp32 scatter ----
// Block = 256 thr (4 waves), 128 consecutive edges. Wave handles one edge per
// iter; lane covers cols {lane, lane+64} (every load/atomic instruction is a
// dense 256 B span). S = silu(ea@W1+b1) batch-shared; X0/X1 = x row sums.
__global__ __launch_bounds__(256) void scatter_kernel(
        const float* __restrict__ x, const float* __restrict__ ea,
        const float* __restrict__ W1, const float* __restrict__ b1,
        const int* __restrict__ recv,
        float* __restrict__ aggS, float* __restrict__ aggX,
        int* __restrict__ cnt) {
    int tid  = threadIdx.x;
    int wave = tid >> 6;
    int lane = tid & 63;
    int ebase = blockIdx.x * 128 + wave;

    // per-lane weight columns: c0 = lane, c1 = lane + 64
    float w0a = W1[lane],       w1a = W1[128 + lane];
    float w2a = W1[256 + lane], w3a = W1[384 + lane];
    float bba = b1[lane];
    float w0b = W1[64 + lane],       w1b = W1[192 + lane];
    float w2b = W1[320 + lane],      w3b = W1[448 + lane];
    float bbb = b1[64 + lane];
    const float* xb = x + (size_t)E_ * 128;

    #pragma unroll 2
    for (int it = 0; it < 32; ++it) {
        int e = ebase + it * 4;
        int r = recv[e];
        float4 q = *(const float4*)(ea + (size_t)e * 4);
        const float* xr0 = x  + (size_t)e * 128;
        const float* xr1 = xb + (size_t)e * 128;
        float xa0 = xr0[lane];
        float xa1 = xr0[64 + lane];
        float xc0 = xr1[lane];
        float xc1 = xr1[64 + lane];
        float p0 = fmaf(q.x, w0a, fmaf(q.y, w1a, fmaf(q.z, w2a, fmaf(q.w, w3a, bba))));
        float p1 = fmaf(q.x, w0b, fmaf(q.y, w1b, fmaf(q.z, w2b, fmaf(q.w, w3b, bbb))));
        float s0 = p0 / (1.f + __expf(-p0));
        float s1 = p1 / (1.f + __expf(-p1));
        float* Sr  = aggS + (size_t)r * 128;
        float* X0r = aggX + (size_t)r * 128;
        float* X1r = aggX + ((size_t)NREC_ + r) * 128;
        atomicAdd(Sr  + lane,      s0);
        atomicAdd(Sr  + 64 + lane, s1);
        atomicAdd(X0r + lane,      xa0);
        atomicAdd(X0r + 64 + lane, xa1);
        atomicAdd(X1r + lane,      xc0);
        atomicAdd(X1r + 64 + lane, xc1);
        if (lane == 0) atomicAdd(&cnt[r], 1);
    }
}

// ---- FFN: out = silu(agg @ L1comb + c1 + cnt*v) @ L2 + c2 ----
// Block owns 8 receivers; A-tile 16 rows = 8 receivers x 2 batches
// (rows 0-7 batch0 [S|X0], rows 8-15 batch1 [S|X1]); waves split 16 N-tiles.
__global__ __launch_bounds__(128) void ffn_kernel(
        const float* __restrict__ aggS, const float* __restrict__ aggX,
        const unsigned short* __restrict__ L1T, const float* __restrict__ c1,
        const unsigned short* __restrict__ L2T, const float* __restrict__ c2,
        const float* __restrict__ v, const int* __restrict__ cnt,
        float* __restrict__ out) {
    __shared__ unsigned short T[16][264];
    int tid  = threadIdx.x;          // 0..127
    int r0   = blockIdx.x * 8;
    int wave = tid >> 6;             // nt half (0..1)
    int lane = tid & 63;
    int quad = lane >> 4;
    int l16  = lane & 15;

    float cntv[4];
    #pragma unroll
    for (int rr = 0; rr < 4; ++rr) {
        int m = quad * 4 + rr;               // M-row 0..15
        cntv[rr] = (float)cnt[r0 + (m & 7)];
    }

    // Build A fragments from fp32 planes (cvt to bf16)
    short8 afrag[8];
    {
        int row8 = l16 & 7;
        const float* sp = aggS + (size_t)(r0 + row8) * 128;
        const float* xp = aggX + ((size_t)(l16 >> 3) * NREC_ + r0 + row8) * 128;
        #pragma unroll
        for (int ks = 0; ks < 4; ++ks) {
            int cb = quad * 8 + ks * 32;
            float4 f0 = *(const float4*)(sp + cb);
            float4 f1 = *(const float4*)(sp + cb + 4);
            short8 fa = {(short)f2bf(f0.x), (short)f2bf(f0.y), (short)f2bf(f0.z), (short)f2bf(f0.w),
                         (short)f2bf(f1.x), (short)f2bf(f1.y), (short)f2bf(f1.z), (short)f2bf(f1.w)};
            afrag[ks] = fa;
            float4 g0 = *(const float4*)(xp + cb);
            float4 g1 = *(const float4*)(xp + cb + 4);
            short8 fb = {(short)f2bf(g0.x), (short)f2bf(g0.y), (short)f2bf(g0.z), (short)f2bf(g0.w),
                         (short)f2bf(g1.x), (short)f2bf(g1.y), (short)f2bf(g1.z), (short)f2bf(g1.w)};
            afrag[ks + 4] = fb;
        }
    }

    #pragma unroll 2
    for (int nt = wave * 8; nt < wave * 8 + 8; ++nt) {
        f32x4 acc = {0.f, 0.f, 0.f, 0.f};
        const unsigned short* bptr = L1T + (size_t)(nt * 16 + l16) * 256 + quad * 8;
        #pragma unroll
        for (int ks = 0; ks < 8; ++ks) {
            short8 bfrag = *(const short8*)(bptr + ks * 32);
            acc = __builtin_amdgcn_mfma_f32_16x16x32_bf16(afrag[ks], bfrag, acc, 0, 0, 0);
        }
        #pragma unroll
        for (int rr = 0; rr < 4; ++rr) {
            int col = nt * 16 + l16;
            float pv = acc[rr] + c1[col] + cntv[rr] * v[col];
            pv = pv / (1.f + __expf(-pv));
            T[quad * 4 + rr][col] = f2bf(pv);
        }
    }
    __syncthreads();

    short8 afrag2[8];
    #pragma unroll
    for (int ks = 0; ks < 8; ++ks)
        afrag2[ks] = *(const short8*)&T[l16][ks * 32 + quad * 8];

    #pragma unroll 2
    for (int nt = wave * 8; nt < wave * 8 + 8; ++nt) {
        f32x4 acc = {0.f, 0.f, 0.f, 0.f};
        const unsigned short* bptr = L2T + (size_t)(nt * 16 + l16) * 256 + quad * 8;
        #pragma unroll
        for (int ks = 0; ks < 8; ++ks) {
            short8 bfrag = *(const short8*)(bptr + ks * 32);
            acc = __builtin_amdgcn_mfma_f32_16x16x32_bf16(afrag2[ks], bfrag, acc, 0, 0, 0);
        }
        #pragma unroll
        for (int rr = 0; rr < 4; ++rr) {
            int m = quad * 4 + rr;           // M-row 0..15
            int b = m >> 3;
            int r = r0 + (m & 7);
            int col = nt * 16 + l16;
            out[((size_t)b * NREC_ + r) * 256 + col] = acc[rr] + c2[col];
        }
    }
}

extern "C" void kernel_launch(void* const* d_in, const int* in_sizes, int n_in,
                              void* d_out, int out_size, void* d_ws, size_t ws_size,
                              hipStream_t stream) {
    const float* x          = (const float*)d_in[0];
    const float* edge_attr  = (const float*)d_in[1];
    const int*   edge_index = (const int*)d_in[2];
    const float* W1 = (const float*)d_in[3];
    const float* b1 = (const float*)d_in[4];
    const float* W2 = (const float*)d_in[5];
    const float* b2 = (const float*)d_in[6];
    const float* L1 = (const float*)d_in[7];
    const float* c1 = (const float*)d_in[8];
    const float* L2 = (const float*)d_in[9];
    const float* c2 = (const float*)d_in[10];
    float* out = (float*)d_out;

    // workspace layout (16B aligned): zero-init region first, then weights
    float* aggS = (float*)d_ws;                        // NREC*128 fp32
    float* aggX = aggS + (size_t)NREC_ * 128;          // 2*NREC*128 fp32
    int*   cnt  = (int*)(aggX + (size_t)2 * NREC_ * 128);  // NREC ints
    unsigned short* L1T = (unsigned short*)(cnt + NREC_);  // 65536
    unsigned short* L2T = L1T + 256 * 256;             // 65536
    float* v = (float*)(L2T + 256 * 256);              // 256

    const int* recv = edge_index + E_;   // edge_index[1]

    size_t zbytes = (size_t)3 * NREC_ * 128 * sizeof(float) + NREC_ * sizeof(int);
    hipMemsetAsync(aggS, 0, zbytes, stream);
    pre_w<<<512, 256, 0, stream>>>(W2, b2, L1, L2, L1T, L2T, v);
    scatter_kernel<<<E_ / 128, 256, 0, stream>>>(x, edge_attr, W1, b1, recv,
                                                 aggS, aggX, cnt);
    ffn_kernel<<<NREC_ / 8, 128, 0, stream>>>(aggS, aggX, L1T, c1, L2T, c2, v,
                                              cnt, out);
}